// Round 1
// baseline (245.986 us; speedup 1.0000x reference)
//
#include <hip/hip_runtime.h>

#define B_   16
#define C_   96
#define N_   4096
#define BN_  65536
#define K_   16
#define E_   (BN_ * K_)

// ---------------------------------------------------------------------------
// Kernel A: transpose x [B, C, N] -> feats [BN, C]  (node-major rows, 384 B)
// ---------------------------------------------------------------------------
__global__ __launch_bounds__(256) void transpose_k(const float* __restrict__ x,
                                                   float* __restrict__ feats) {
    __shared__ float tile[32][65];  // +1 pad: conflict-free both phases
    int b  = blockIdx.z;
    int c0 = blockIdx.y * 32;
    int n0 = blockIdx.x * 64;
    const float* xp = x + (size_t)b * C_ * N_;
    // load: 32 c-rows x 64 n, coalesced along n
    for (int t = threadIdx.x; t < 32 * 64; t += 256) {
        int c = t >> 6, n = t & 63;
        tile[c][n] = xp[(size_t)(c0 + c) * N_ + n0 + n];
    }
    __syncthreads();
    // store: coalesced along c (32 consecutive floats per node)
    float* fp = feats + ((size_t)b * N_ + n0) * C_ + c0;
    for (int t = threadIdx.x; t < 32 * 64; t += 256) {
        int n = t >> 5, c = t & 31;
        fp[(size_t)n * C_ + c] = tile[c][n];
    }
}

// ---------------------------------------------------------------------------
// Kernel B: per-node max over 16 gathered rows, minus own row.
// 4 threads per node (interleaved float4 chunks r, r+4, ..., r+20),
// 64 nodes per 256-thread block. Gather reads are 64 B-contiguous per node.
// ---------------------------------------------------------------------------
__global__ __launch_bounds__(256) void gather_max_k(const float* __restrict__ feats,
                                                    const int* __restrict__ src,
                                                    float* __restrict__ agg) {
    int tid = threadIdx.x;
    int ln  = tid >> 2;          // local node 0..63
    int r   = tid & 3;           // chunk group 0..3
    size_t i = (size_t)blockIdx.x * 64 + ln;
    const int* s = src + i * K_;

    float4 m[6];
#pragma unroll
    for (int j = 0; j < 6; j++)
        m[j] = make_float4(-3.0e38f, -3.0e38f, -3.0e38f, -3.0e38f);

#pragma unroll
    for (int q = 0; q < 4; q++) {
        int4 iv = ((const int4*)s)[q];
        int ids[4] = {iv.x, iv.y, iv.z, iv.w};
#pragma unroll
        for (int kk = 0; kk < 4; kk++) {   // static indexing (no scratch)
            const float4* sr = (const float4*)(feats + (size_t)ids[kk] * C_);
#pragma unroll
            for (int j = 0; j < 6; j++) {
                float4 v = sr[r + 4 * j];
                m[j].x = fmaxf(m[j].x, v.x);
                m[j].y = fmaxf(m[j].y, v.y);
                m[j].z = fmaxf(m[j].z, v.z);
                m[j].w = fmaxf(m[j].w, v.w);
            }
        }
    }

    const float4* fr = (const float4*)(feats + i * C_);
    float4* ar = (float4*)(agg + i * C_);
#pragma unroll
    for (int j = 0; j < 6; j++) {
        float4 own = fr[r + 4 * j];
        ar[r + 4 * j] = make_float4(m[j].x - own.x, m[j].y - own.y,
                                    m[j].z - own.z, m[j].w - own.w);
    }
}

// ---------------------------------------------------------------------------
// Kernel C: out[b,o,n] = relu(bc[o] + sum_c W[o,2c]*x[b,c,n] + W[o,2c+1]*agg[i,c])
// Block: 256 threads (4 waves), tile = 64 consecutive nodes x all 96 outputs.
// Each wave owns 24 output rows, computed 8 at a time (register blocking).
// ---------------------------------------------------------------------------
__global__ __launch_bounds__(256) void conv_k(const float* __restrict__ x,
                                              const float* __restrict__ agg,
                                              const float* __restrict__ Wc,
                                              const float* __restrict__ bc,
                                              float* __restrict__ out) {
    __shared__ float xT[96][64];   // [c][n] — writes/reads conflict-free
    __shared__ float aT[96][65];   // +1 pad: transposed scatter writes
    int bidx = blockIdx.x;
    int b  = bidx >> 6;
    int n0 = (bidx & 63) << 6;

    const float* xp = x + (size_t)b * C_ * N_ + n0;
    for (int t = threadIdx.x; t < 96 * 16; t += 256) {
        int c = t >> 4, q = t & 15;
        float4 v = *(const float4*)(xp + (size_t)c * N_ + q * 4);
        xT[c][q * 4 + 0] = v.x; xT[c][q * 4 + 1] = v.y;
        xT[c][q * 4 + 2] = v.z; xT[c][q * 4 + 3] = v.w;
    }
    const float* ap = agg + ((size_t)b * N_ + n0) * C_;
    for (int t = threadIdx.x; t < 64 * 24; t += 256) {
        int n = t / 24, q = t % 24;
        float4 v = *(const float4*)(ap + (size_t)n * C_ + q * 4);
        aT[q * 4 + 0][n] = v.x; aT[q * 4 + 1][n] = v.y;
        aT[q * 4 + 2][n] = v.z; aT[q * 4 + 3][n] = v.w;
    }
    __syncthreads();

    int wave = threadIdx.x >> 6;
    int lane = threadIdx.x & 63;
    float* op = out + (size_t)b * C_ * N_ + n0 + lane;

#pragma unroll
    for (int g = 0; g < 3; g++) {
        int o0 = wave * 24 + g * 8;
        float acc[8];
#pragma unroll
        for (int u = 0; u < 8; u++) acc[u] = bc[o0 + u];
        for (int c = 0; c < 96; c++) {
            float xv = xT[c][lane];
            float av = aT[c][lane];
#pragma unroll
            for (int u = 0; u < 8; u++) {
                float2 w = *(const float2*)(Wc + (size_t)(o0 + u) * 192 + 2 * c);
                acc[u] += w.x * xv + w.y * av;
            }
        }
#pragma unroll
        for (int u = 0; u < 8; u++) {
            op[(size_t)(o0 + u) * N_] = fmaxf(acc[u], 0.0f);
        }
    }
}

// ---------------------------------------------------------------------------
extern "C" void kernel_launch(void* const* d_in, const int* in_sizes, int n_in,
                              void* d_out, int out_size, void* d_ws, size_t ws_size,
                              hipStream_t stream) {
    const float* x   = (const float*)d_in[0];
    const int*   ei  = (const int*)d_in[1];     // [2, E] int32; row1 = src
    const float* Wc  = (const float*)d_in[2];   // [96, 192] interleaved
    const float* bc  = (const float*)d_in[3];   // [96]
    float* out = (float*)d_out;

    const int* src = ei + E_;

    float* feats = (float*)d_ws;                         // [BN, 96]
    float* agg   = feats + (size_t)BN_ * C_;             // [BN, 96]

    dim3 gA(N_ / 64, C_ / 32, B_);
    transpose_k<<<gA, 256, 0, stream>>>(x, feats);

    gather_max_k<<<BN_ / 64, 256, 0, stream>>>(feats, src, agg);

    conv_k<<<BN_ / 64, 256, 0, stream>>>(x, agg, Wc, bc, out);
}